// Round 4
// baseline (141.675 us; speedup 1.0000x reference)
//
#include <hip/hip_runtime.h>
#include <math.h>

// Deepmd angular descriptor. Established by rounds 0-3:
//   - all float inputs are float32 (rounds 2==3 bit-identical under per-tensor
//     dtype sniff => sniff chose f32 for every tensor; bf16 data cannot evade
//     the sniff)
//   - output dtype: float32 (reference output dtype = positions.dtype = f32;
//     bf16 writes into the f32 buffer left rounds 2/3 at the same structural
//     error regardless of input fixes)
// Shapes: B=8, N=4096, M=96, out width 3*N_ANGULAR = 384.
#define M_NB  96
#define OUT_W 384
#define PPB   2            // (b,n) pairs per block; 2*96 = 192 threads = 3 waves

__global__ __launch_bounds__(PPB * M_NB) void deepmd_angular_kernel(
    const float* __restrict__ positions,  // [B,N,3]
    const float* __restrict__ cell,       // [B,3,3]
    const float* __restrict__ offsets,    // [B,N,M,3]
    const float* __restrict__ mask,       // [B,N,M]
    const int*   __restrict__ neighbors,  // [B,N,M]
    float*       __restrict__ out,        // [B,N,OUT_W]  float32
    int N)
{
    __shared__ float cut_s[PPB][M_NB];
    __shared__ float out_s[PPB][3 * M_NB];   // 288 data slots per pair

    const int m  = threadIdx.x;              // 0..95  neighbor index
    const int pr = threadIdx.y;              // 0..PPB-1
    const int p  = blockIdx.x * PPB + pr;    // global (b,n) pair index
    const int b  = p / N;

    // ---- per-neighbor inputs ----
    const long base_nm = (long)p * M_NB + m;
    const int   j   = neighbors[base_nm];
    const float msk = mask[base_nm];
    const float o0  = offsets[base_nm * 3 + 0];
    const float o1  = offsets[base_nm * 3 + 1];
    const float o2  = offsets[base_nm * 3 + 2];

    const float* cb = cell + (long)b * 9;    // row-major [3][3]
    const float c00 = cb[0], c01 = cb[1], c02 = cb[2];
    const float c10 = cb[3], c11 = cb[4], c12 = cb[5];
    const float c20 = cb[6], c21 = cb[7], c22 = cb[8];

    const float* pi_ = positions + (long)p * 3;
    const float* pj_ = positions + (long)(b * N + j) * 3;

    // dis_vec = pos_j - pos_i + offsets @ cell   (einsum bnmi,bij->bnmj)
    const float dx = pj_[0] - pi_[0] + o0 * c00 + o1 * c10 + o2 * c20;
    const float dy = pj_[1] - pi_[1] + o0 * c01 + o1 * c11 + o2 * c21;
    const float dz = pj_[2] - pi_[2] + o0 * c02 + o1 * c12 + o2 * c22;

    const float d = sqrtf(dx * dx + dy * dy + dz * dz + 1e-12f);

    // cut = mask ? ((d<rc) ? 0.5*(cos(pi*d/rc)+1)/d : 0) : 0
    float cut = 0.0f;
    if (msk != 0.0f && d < 6.0f) {
        cut = 0.5f * (cosf(d * 0.52359877559829887f) + 1.0f) / d;
    }

    cut_s[pr][m] = cut;
    // zero-init row (insurance; scatter below is a bijection)
    out_s[pr][m]          = 0.0f;
    out_s[pr][m + M_NB]   = 0.0f;
    out_s[pr][m + 2*M_NB] = 0.0f;
    __syncthreads();

    // ---- stable descending rank over all 96 entries ----
    // rank(m) = #{k: cut_k > cut_m} + #{k<m: cut_k == cut_m}
    // scatter-by-rank == gather-by-stable-argsort(-cut); rank is a bijection.
    int rank = 0;
    #pragma unroll 8
    for (int k = 0; k < M_NB; ++k) {
        const float ck = cut_s[pr][k];           // LDS broadcast read
        rank += (ck > cut) || (ck == cut && k < m);
    }
    out_s[pr][rank * 3 + 0] = cut * dx;
    out_s[pr][rank * 3 + 1] = cut * dy;
    out_s[pr][rank * 3 + 2] = cut * dz;
    __syncthreads();

    // ---- emit row: 384 f32 = 96 x float4 (16 B/thread, coalesced) ----
    float4 v;
    if (4 * m < 3 * M_NB) {
        v.x = out_s[pr][4 * m + 0];
        v.y = out_s[pr][4 * m + 1];
        v.z = out_s[pr][4 * m + 2];
        v.w = out_s[pr][4 * m + 3];
    } else {
        v.x = 0.0f; v.y = 0.0f; v.z = 0.0f; v.w = 0.0f;  // zero pad [288, 384)
    }
    ((float4*)(out + (size_t)p * OUT_W))[m] = v;
}

extern "C" void kernel_launch(void* const* d_in, const int* in_sizes, int n_in,
                              void* d_out, int out_size, void* d_ws, size_t ws_size,
                              hipStream_t stream) {
    const float* positions = (const float*)d_in[0];
    const float* cell      = (const float*)d_in[1];
    const float* offsets   = (const float*)d_in[2];
    const float* mask      = (const float*)d_in[3];
    const int*   neighbors = (const int*)d_in[4];
    float*       out       = (float*)d_out;

    const int BN = in_sizes[0] / 3;        // B*N = 32768
    const int B  = in_sizes[1] / 9;        // 8
    const int N  = BN / B;                 // 4096

    dim3 block(M_NB, PPB, 1);              // 96 x 2 = 192 threads
    dim3 grid(BN / PPB, 1, 1);             // 16384 blocks
    deepmd_angular_kernel<<<grid, block, 0, stream>>>(
        positions, cell, offsets, mask, neighbors, out, N);
}

// Round 5
// 128.971 us; speedup vs baseline: 1.0985x; 1.0985x over previous
//
#include <hip/hip_runtime.h>
#include <math.h>

// Deepmd angular descriptor, f32 in / f32 out (established rounds 0-4).
// Shapes: B=8, N=4096, M=96, out width 3*N_ANGULAR = 384.
//
// R5 change vs R4 (52.8 us, VALUBusy 67%): the 96-iter stable-rank loop now
// runs only for lanes with cut != 0 (~0.45% of lanes; ~75% of waves skip it
// entirely via s_cbranch_execz). Zero-cut entries sort strictly after every
// nonzero entry and contribute exact zeros wherever they land, so scattering
// only nonzero lanes into a pre-zeroed LDS row is bit-identical to the full
// bijective scatter. Rank-loop LDS reads vectorized to float4.
#define M_NB  96
#define OUT_W 384
#define PPB   2            // (b,n) pairs per block; 2*96 = 192 threads = 3 waves

__global__ __launch_bounds__(PPB * M_NB) void deepmd_angular_kernel(
    const float* __restrict__ positions,  // [B,N,3]
    const float* __restrict__ cell,       // [B,3,3]
    const float* __restrict__ offsets,    // [B,N,M,3]
    const float* __restrict__ mask,       // [B,N,M]
    const int*   __restrict__ neighbors,  // [B,N,M]
    float*       __restrict__ out,        // [B,N,OUT_W]
    int N)
{
    __shared__ float cut_s[PPB][M_NB];
    __shared__ float out_s[PPB][3 * M_NB];   // 288 data slots per pair

    const int m  = threadIdx.x;              // 0..95  neighbor index
    const int pr = threadIdx.y;              // 0..PPB-1
    const int p  = blockIdx.x * PPB + pr;    // global (b,n) pair index
    const int b  = p / N;

    // ---- per-neighbor inputs ----
    const long base_nm = (long)p * M_NB + m;
    const int   j   = neighbors[base_nm];
    const float msk = mask[base_nm];
    const float o0  = offsets[base_nm * 3 + 0];
    const float o1  = offsets[base_nm * 3 + 1];
    const float o2  = offsets[base_nm * 3 + 2];

    const float* cb = cell + (long)b * 9;    // row-major [3][3]
    const float c00 = cb[0], c01 = cb[1], c02 = cb[2];
    const float c10 = cb[3], c11 = cb[4], c12 = cb[5];
    const float c20 = cb[6], c21 = cb[7], c22 = cb[8];

    const float* pi_ = positions + (long)p * 3;
    const float* pj_ = positions + (long)(b * N + j) * 3;

    // dis_vec = pos_j - pos_i + offsets @ cell   (einsum bnmi,bij->bnmj)
    const float dx = pj_[0] - pi_[0] + o0 * c00 + o1 * c10 + o2 * c20;
    const float dy = pj_[1] - pi_[1] + o0 * c01 + o1 * c11 + o2 * c21;
    const float dz = pj_[2] - pi_[2] + o0 * c02 + o1 * c12 + o2 * c22;

    const float d = sqrtf(dx * dx + dy * dy + dz * dz + 1e-12f);

    // cut = mask ? ((d<rc) ? 0.5*(cos(pi*d/rc)+1)/d : 0) : 0
    float cut = 0.0f;
    if (msk != 0.0f && d < 6.0f) {
        cut = 0.5f * (cosf(d * 0.52359877559829887f) + 1.0f) / d;
    }

    cut_s[pr][m] = cut;
    // zero the 288-float row (3 slots/thread, conflict-free)
    out_s[pr][m]          = 0.0f;
    out_s[pr][m + M_NB]   = 0.0f;
    out_s[pr][m + 2*M_NB] = 0.0f;
    __syncthreads();

    // ---- stable descending rank, nonzero lanes only (~0.45%) ----
    // rank(m) = #{k: cut_k > cut_m} + #{k<m: cut_k == cut_m}
    // == position under stable argsort(-cut). Zero lanes: their slots stay 0,
    // exactly what they'd have written.
    if (cut != 0.0f) {
        int rank = 0;
        const float4* c4 = (const float4*)cut_s[pr];
        #pragma unroll
        for (int k4 = 0; k4 < M_NB / 4; ++k4) {
            const float4 c = c4[k4];             // ds_read_b128 broadcast
            const int k = 4 * k4;
            rank += (c.x > cut) || (c.x == cut && k + 0 < m);
            rank += (c.y > cut) || (c.y == cut && k + 1 < m);
            rank += (c.z > cut) || (c.z == cut && k + 2 < m);
            rank += (c.w > cut) || (c.w == cut && k + 3 < m);
        }
        out_s[pr][rank * 3 + 0] = cut * dx;
        out_s[pr][rank * 3 + 1] = cut * dy;
        out_s[pr][rank * 3 + 2] = cut * dz;
    }
    __syncthreads();

    // ---- emit row: 384 f32 = 96 x float4 (16 B/thread, coalesced) ----
    float4 v;
    if (4 * m < 3 * M_NB) {
        v.x = out_s[pr][4 * m + 0];
        v.y = out_s[pr][4 * m + 1];
        v.z = out_s[pr][4 * m + 2];
        v.w = out_s[pr][4 * m + 3];
    } else {
        v.x = 0.0f; v.y = 0.0f; v.z = 0.0f; v.w = 0.0f;  // zero pad [288, 384)
    }
    ((float4*)(out + (size_t)p * OUT_W))[m] = v;
}

extern "C" void kernel_launch(void* const* d_in, const int* in_sizes, int n_in,
                              void* d_out, int out_size, void* d_ws, size_t ws_size,
                              hipStream_t stream) {
    const float* positions = (const float*)d_in[0];
    const float* cell      = (const float*)d_in[1];
    const float* offsets   = (const float*)d_in[2];
    const float* mask      = (const float*)d_in[3];
    const int*   neighbors = (const int*)d_in[4];
    float*       out       = (float*)d_out;

    const int BN = in_sizes[0] / 3;        // B*N = 32768
    const int B  = in_sizes[1] / 9;        // 8
    const int N  = BN / B;                 // 4096

    dim3 block(M_NB, PPB, 1);              // 96 x 2 = 192 threads
    dim3 grid(BN / PPB, 1, 1);             // 16384 blocks
    deepmd_angular_kernel<<<grid, block, 0, stream>>>(
        positions, cell, offsets, mask, neighbors, out, N);
}